// Round 1
// baseline (1788.511 us; speedup 1.0000x reference)
//
#include <hip/hip_runtime.h>
#include <stdint.h>

// Binary-weight MLP forward, exact int8 digit-plane formulation.
//   h = x @ sign(W1)^T  -> sign(h) @ sign(W2)^T -> sigmoid, threshold
// x is quantized to v = rint(x * 2^26) (exact via double), split into 4
// signed int8 digits; 4 plane-GEMMs on mfma_i32_32x32x32_i8 (exact i32
// accumulation) recombine to the exact sign of the quantized row-dot.
// Digits are written IN PLACE into d_in[0] (harness restores pristine
// inputs before every launch). W1 signs pre-packed into ws in MFMA
// fragment order so GEMM LDS staging is linear b128 copies.

typedef int v4i  __attribute__((ext_vector_type(4)));
typedef int v16i __attribute__((ext_vector_type(16)));

#define B_ROWS   16384
#define DIM      4096
#define MT       64      // workgroup m-tile
#define NT       128     // workgroup n-tile
#define KT       64      // k-tile

// ---------------- pack x -> 4 digit planes, in place, one block per row ----
__global__ void pack_x_kernel(float* __restrict__ x) {
    const int b = blockIdx.x, t = threadIdx.x;
    float* row = x + (size_t)b * DIM;
    float f[16];
#pragma unroll
    for (int i = 0; i < 4; ++i) {
        float4 v = ((const float4*)(row + t * 16))[i];
        f[i*4+0] = v.x; f[i*4+1] = v.y; f[i*4+2] = v.z; f[i*4+3] = v.w;
    }
    __syncthreads();   // all reads of this row complete before any write
    uint32_t wds[4][4]; // [digit][word]
#pragma unroll
    for (int j = 0; j < 4; ++j) {
#pragma unroll
        for (int d = 0; d < 4; ++d) wds[d][j] = 0u;
#pragma unroll
        for (int i = 0; i < 4; ++i) {
            int v = __double2int_rn((double)f[j*4+i] * 67108864.0); // 2^26
#pragma unroll
            for (int d = 0; d < 4; ++d) {
                int bb = (int)(int8_t)(v & 0xff);
                wds[d][j] |= (uint32_t)(bb & 0xff) << (8 * i);
                v = (v - bb) >> 8;   // exact
            }
        }
    }
    int8_t* rowb = (int8_t*)row;  // row = 16384 bytes = 4 planes x 4096
#pragma unroll
    for (int d = 0; d < 4; ++d) {
        int4 o; o.x = (int)wds[d][0]; o.y = (int)wds[d][1];
        o.z = (int)wds[d][2]; o.w = (int)wds[d][3];
        *(int4*)(rowb + d * DIM + t * 16) = o;
    }
}

// ---------------- pack W1 signs into MFMA-fragment-ordered blocks ----------
// ws_B offset(n,k): block (nb= n>>7, kt= k>>6) of 8192B;
// within: nsub=(n>>5)&3 (2048B), ks=(k>>5)&1 (1024B),
//         L = (n&31)|(((k>>4)&1)<<5) (16B), byte = k&15.
__global__ void pack_w1_kernel(const float* __restrict__ W1, int8_t* __restrict__ wsB) {
    const int tg = blockIdx.x * 256 + threadIdx.x;   // [0, 4096*256)
    const int n  = tg >> 8;
    const int k0 = (tg & 255) << 4;
    const float* src = W1 + (size_t)n * DIM + k0;
    uint32_t w[4];
#pragma unroll
    for (int j = 0; j < 4; ++j) {
        float4 v = ((const float4*)src)[j];
        uint32_t b0 = (v.x >= 0.f) ? 0x01u : 0xFFu;
        uint32_t b1 = (v.y >= 0.f) ? 0x01u : 0xFFu;
        uint32_t b2 = (v.z >= 0.f) ? 0x01u : 0xFFu;
        uint32_t b3 = (v.w >= 0.f) ? 0x01u : 0xFFu;
        w[j] = b0 | (b1 << 8) | (b2 << 16) | (b3 << 24);
    }
    const int nb = n >> 7, kt = k0 >> 6;
    const int nsub = (n >> 5) & 3, ks = (k0 >> 5) & 1;
    const int L = (n & 31) | (((k0 >> 4) & 1) << 5);
    const size_t off = ((size_t)(nb * 64 + kt) << 13) + (nsub << 11) + (ks << 10) + (L << 4);
    int4 o; o.x = (int)w[0]; o.y = (int)w[1]; o.z = (int)w[2]; o.w = (int)w[3];
    *(int4*)(wsB + off) = o;
}

__global__ void pack_w2_kernel(const float* __restrict__ W2, int8_t* __restrict__ w2s) {
    const int j = blockIdx.x * 256 + threadIdx.x;
    if (j < DIM) w2s[j] = (W2[j] >= 0.f) ? (int8_t)1 : (int8_t)-1;
}

// ---------------- fused GEMM: 4 digit planes, epilogue sign*w2 -> logit ----
__launch_bounds__(256, 2)
__global__ void gemm_kernel(const int8_t* __restrict__ xq,
                            const int8_t* __restrict__ wsB,
                            const int8_t* __restrict__ w2s,
                            int* __restrict__ logit) {
    __shared__ __align__(16) int8_t aT[4 * MT * KT];   // 16 KB: [d][msub][ks][L][16]
    __shared__ __align__(16) int8_t bT[NT * KT];       //  8 KB: [nsub][ks][L][16]

    const int bid = blockIdx.x;
    const int nb = bid & 31, mb = bid >> 5;            // n fastest: A-block L2/L3 reuse
    const int t = threadIdx.x, lane = t & 63, w = t >> 6;
    const int wy = w >> 1, wx = w & 1;                 // wave tile: 32(m) x 64(n)

    v16i acc[2][4];
#pragma unroll
    for (int n = 0; n < 2; ++n)
#pragma unroll
        for (int d = 0; d < 4; ++d)
#pragma unroll
            for (int i = 0; i < 16; ++i) acc[n][d][i] = 0;

    // A staging: wave w stages plane d=w, lane = m (64 rows)
    const int8_t* aSrc = xq + (size_t)(mb * MT + lane) * (4 * DIM) + w * DIM;
    const int8_t* bSrc = wsB + ((size_t)(nb * 64) << 13) + t * 32;
    const int aDst = w * (MT * KT) + ((lane >> 5) << 11) + ((lane & 31) << 4);

    for (int kt = 0; kt < DIM / KT; ++kt) {
#pragma unroll
        for (int k16 = 0; k16 < 4; ++k16) {
            v4i v = *(const v4i*)(aSrc + kt * KT + k16 * 16);
            *(v4i*)(aT + aDst + ((k16 >> 1) << 10) + ((k16 & 1) << 9)) = v;
        }
        {
            const v4i* s = (const v4i*)(bSrc + ((size_t)kt << 13));
            *(v4i*)(bT + t * 32)      = s[0];
            *(v4i*)(bT + t * 32 + 16) = s[1];
        }
        __syncthreads();
#pragma unroll
        for (int s = 0; s < 2; ++s) {
            v4i af[4], bf[2];
#pragma unroll
            for (int d = 0; d < 4; ++d)
                af[d] = *(const v4i*)(aT + d * (MT * KT) + (wy << 11) + (s << 10) + (lane << 4));
#pragma unroll
            for (int n = 0; n < 2; ++n)
                bf[n] = *(const v4i*)(bT + ((wx * 2 + n) << 11) + (s << 10) + (lane << 4));
#pragma unroll
            for (int n = 0; n < 2; ++n)
#pragma unroll
                for (int d = 0; d < 4; ++d)
                    acc[n][d] = __builtin_amdgcn_mfma_i32_32x32x32_i8(af[d], bf[n], acc[n][d], 0, 0, 0);
        }
        __syncthreads();
    }

    // epilogue: recombine digits -> exact sign -> *sign(W2) -> row sums -> atomic
    const int half = lane >> 5, col = lane & 31;
    int psum[16];
#pragma unroll
    for (int r = 0; r < 16; ++r) psum[r] = 0;
#pragma unroll
    for (int n = 0; n < 2; ++n) {
        const int j = nb * NT + wx * 64 + n * 32 + col;
        const int w2v = (int)w2s[j];
#pragma unroll
        for (int r = 0; r < 16; ++r) {
            long long h = (long long)acc[n][0][r]
                        + ((long long)acc[n][1][r] << 8)
                        + ((long long)acc[n][2][r] << 16)
                        + ((long long)acc[n][3][r] << 24);
            psum[r] += (h >= 0) ? w2v : -w2v;
        }
    }
#pragma unroll
    for (int r = 0; r < 16; ++r) {
#pragma unroll
        for (int m = 1; m <= 16; m <<= 1)
            psum[r] += __shfl_xor(psum[r], m, 64);
    }
    if (col == 0) {
        const int rowBase = mb * MT + wy * 32 + 4 * half;
#pragma unroll
        for (int r = 0; r < 16; ++r)
            atomicAdd(logit + rowBase + (r & 3) + 8 * (r >> 2), psum[r]);
    }
}

// ---------------- finalize: sigmoid + threshold ----------------------------
__global__ void finalize_kernel(const int* __restrict__ logit, float* __restrict__ out) {
    const int b = blockIdx.x * 256 + threadIdx.x;
    if (b < B_ROWS) {
        const int l = logit[b];
        out[b]          = 1.f / (1.f + expf(-(float)l));
        out[B_ROWS + b] = (l >= 0) ? 1.f : 0.f;
    }
}

extern "C" void kernel_launch(void* const* d_in, const int* in_sizes, int n_in,
                              void* d_out, int out_size, void* d_ws, size_t ws_size,
                              hipStream_t stream) {
    float*       x   = (float*)d_in[0];        // overwritten in place with digits
    const float* W1  = (const float*)d_in[1];
    const float* W2  = (const float*)d_in[2];
    float*       out = (float*)d_out;

    int8_t* ws   = (int8_t*)d_ws;
    int*    logit = (int*)ws;                  // 16384 * 4 B
    int8_t* w2s  = ws + 65536;                 // 4096 B
    int8_t* wsB  = ws + 69632;                 // 16 MiB packed W1 signs

    hipMemsetAsync(logit, 0, B_ROWS * sizeof(int), stream);
    pack_x_kernel<<<B_ROWS, 256, 0, stream>>>(x);
    pack_w1_kernel<<<DIM, 256, 0, stream>>>(W1, wsB);
    pack_w2_kernel<<<16, 256, 0, stream>>>(W2, w2s);
    gemm_kernel<<<(B_ROWS / MT) * (DIM / NT), 256, 0, stream>>>(
        (const int8_t*)x, wsB, w2s, logit);
    finalize_kernel<<<B_ROWS / 256, 256, 0, stream>>>(logit, out);
}